// Round 9
// baseline (839.812 us; speedup 1.0000x reference)
//
#include <hip/hip_runtime.h>

typedef __bf16 bf16_t;
typedef __bf16 bf16x8 __attribute__((ext_vector_type(8)));
typedef float f32x4 __attribute__((ext_vector_type(4)));
typedef float f32x2 __attribute__((ext_vector_type(2)));

#define N_NODES 50000
#define N_PAD   50048   // padded to multiple of 128 for 128-row GEMM tiles
#define N_EDGES 400000
#define D_IN    256
#define D_HID   512
#define D_OUT   128
#define N_LAYERS 4
#define ZROW    N_PAD                  // index of the always-zero hw row (dummy gathers)
#define CSR_CAP (N_EDGES + 3 * N_NODES + 64)  // padded-slot capacity
#define AGG_BLOCKS 2048

#define AS1 __attribute__((address_space(1)))
#define AS3 __attribute__((address_space(3)))

// ---------------- init: zero deg/cursor, dummy-fill csr, zero hw[ZROW], zero dinv pad ----

__global__ void init_misc(int* __restrict__ deg, int* __restrict__ cursor,
                          int* __restrict__ csr_src, float* __restrict__ dinv,
                          bf16_t* __restrict__ hw) {
    int idx = blockIdx.x * blockDim.x + threadIdx.x;
    if (idx < CSR_CAP) csr_src[idx] = ZROW;
    if (idx < N_NODES) { deg[idx] = 0; cursor[idx] = 0; }
    if (idx < N_PAD - N_NODES) dinv[N_NODES + idx] = 0.0f;
    if (idx < D_HID / 2) ((unsigned*)(hw + (size_t)ZROW * D_HID))[idx] = 0u;
}

// ---------------- fp32 -> bf16 conversion (flat, for x) ----------------

__global__ void f32_to_bf16(const float* __restrict__ in, bf16_t* __restrict__ out, int n) {
    int idx = (blockIdx.x * blockDim.x + threadIdx.x) * 4;
    if (idx + 3 < n) {
        float4 v = *reinterpret_cast<const float4*>(in + idx);
        bf16_t o[4] = {(bf16_t)v.x, (bf16_t)v.y, (bf16_t)v.z, (bf16_t)v.w};
        *reinterpret_cast<uint2*>(out + idx) = *reinterpret_cast<const uint2*>(o);
    } else {
        for (int j = idx; j < n; j++) out[j] = (bf16_t)in[j];
    }
}

// ---------------- batched fp32 [R][C] -> bf16 transposed [C][R] for all weights --------
// z: 0 = W1 (256x512), 1..4 = Wc layer (512x512), 5 = W2 (512x128)

__global__ void transpose_all(const float* __restrict__ W1, const float* __restrict__ Wc,
                              const float* __restrict__ W2, bf16_t* __restrict__ W1t,
                              bf16_t* __restrict__ Wct, bf16_t* __restrict__ W2t) {
    const float* in; bf16_t* out; int R, C;
    const int z = blockIdx.z;
    if (z == 0)      { in = W1; out = W1t; R = D_IN;  C = D_HID; }
    else if (z <= 4) { in = Wc + (size_t)(z - 1) * D_HID * D_HID;
                       out = Wct + (size_t)(z - 1) * D_HID * D_HID; R = D_HID; C = D_HID; }
    else             { in = W2; out = W2t; R = D_HID; C = D_OUT; }

    const int c0 = blockIdx.x * 32;
    const int r0 = blockIdx.y * 32;
    if (c0 >= C || r0 >= R) return;
    __shared__ float tile[32][33];
    for (int i = threadIdx.y; i < 32; i += 8)
        tile[i][threadIdx.x] = in[(size_t)(r0 + i) * C + c0 + threadIdx.x];
    __syncthreads();
    for (int i = threadIdx.y; i < 32; i += 8)
        out[(size_t)(c0 + i) * R + r0 + threadIdx.x] = (bf16_t)tile[threadIdx.x][i];
}

// ---------------- degree / padded CSR build ----------------

__global__ void count_deg(const int* __restrict__ dst, int* __restrict__ deg, int E) {
    int e = blockIdx.x * blockDim.x + threadIdx.x;
    if (e < E) atomicAdd(&deg[dst[e]], 1);
}

__global__ void scan_reduce(const int* __restrict__ deg, int* __restrict__ partial, int N) {
    __shared__ int red[256];
    int base = blockIdx.x * 1024;
    int s = 0;
    for (int i = threadIdx.x; i < 1024; i += 256) {
        int idx = base + i;
        s += (idx < N) ? ((deg[idx] + 3) & ~3) : 0;   // padded slots
    }
    red[threadIdx.x] = s;
    __syncthreads();
    for (int off = 128; off > 0; off >>= 1) {
        if (threadIdx.x < off) red[threadIdx.x] += red[threadIdx.x + off];
        __syncthreads();
    }
    if (threadIdx.x == 0) partial[blockIdx.x] = red[0];
}

__global__ void scan_partials(int* __restrict__ partial, int nb,
                              int* __restrict__ row_start, int N) {
    if (threadIdx.x == 0 && blockIdx.x == 0) {
        int acc = 0;
        for (int i = 0; i < nb; i++) { int v = partial[i]; partial[i] = acc; acc += v; }
        row_start[N] = acc;   // total padded slots
    }
}

__global__ void scan_chunks(const int* __restrict__ deg, const int* __restrict__ partial,
                            int* __restrict__ row_start, float* __restrict__ dinv, int N) {
    __shared__ int buf[2][1024];
    int t = threadIdx.x;
    int gid = blockIdx.x * 1024 + t;
    int d = (gid < N) ? deg[gid] : 0;
    int v = (gid < N) ? ((d + 3) & ~3) : 0;           // padded slots
    int cur = 0;
    buf[0][t] = v;
    __syncthreads();
    for (int off = 1; off < 1024; off <<= 1) {
        int nxt = cur ^ 1;
        int val = buf[cur][t];
        if (t >= off) val += buf[cur][t - off];
        buf[nxt][t] = val;
        cur = nxt;
        __syncthreads();
    }
    int incl = buf[cur][t];
    if (gid < N) {
        row_start[gid] = partial[blockIdx.x] + incl - v;  // exclusive
        dinv[gid] = rsqrtf((float)(d + 1));               // +1 self loop
    }
}

__global__ void fill_csr(const int* __restrict__ ei, int E,
                         const int* __restrict__ row_start,
                         int* __restrict__ cursor, int* __restrict__ csr_src) {
    int e = blockIdx.x * blockDim.x + threadIdx.x;
    if (e < E) {
        int s = ei[e];
        int d = ei[E + e];
        int pos = atomicAdd(&cursor[d], 1);
        csr_src[row_start[d] + pos] = s;
    }
}

// ---------------- GEMM: C = act(rowscale * (A @ BT^T) + bias) ----------------
// (unchanged from R8 — 128x128 tile, BK=64, XOR-swizzled LDS, XCD-aware remap)

template <bool F32OUT, bool RELU>
__global__ __launch_bounds__(256, 4) void gemm_tile(
    const bf16_t* __restrict__ A, const bf16_t* __restrict__ BT,
    const float* __restrict__ bias, const float* __restrict__ rowscale,
    void* __restrict__ Cv, int M, int N, int K)
{
    __shared__ __align__(16) char smem[32768];  // sA 16KB + sB 16KB; epilogue reuse
    bf16_t* sA = (bf16_t*)smem;
    bf16_t* sB = (bf16_t*)(smem + 128 * 128);
    bf16_t* sC = (bf16_t*)smem;                 // 64 x 136 bf16 = 17.4 KB

    int bxi, byi;
    if (gridDim.x == 4) {
        const int bid = blockIdx.y * 4 + blockIdx.x;     // dispatch-linear id
        const int T0 = (int)(gridDim.y * 4) & ~31;
        if (bid < T0) { int q = bid >> 5, r = bid & 31; byi = q * 8 + (r & 7); bxi = r >> 3; }
        else          { int t = bid - T0; byi = (T0 >> 2) + (t >> 2); bxi = t & 3; }
    } else { bxi = blockIdx.x; byi = blockIdx.y; }

    const int tid  = threadIdx.x;
    const int lane = tid & 63;
    const int wave = tid >> 6;
    const int bn = bxi * 128;
    const int bm = byi * 128;
    const int wm = (wave & 1) * 64;
    const int wn = (wave >> 1) * 64;
    const int lm = lane & 15;
    const int lq = lane >> 4;

    const int r8 = lane >> 3;
    const int c8 = lane & 7;
    const int ksw = (c8 ^ r8) * 8;              // swizzled k-offset (elements)

    f32x4 acc[4][4] = {};

    const int nkb = K >> 6;
    for (int kb = 0; kb < nkb; kb++) {
        const int k0 = kb * 64;
#pragma unroll
        for (int r = 0; r < 4; r++) {               // A: 16 groups of 8 rows
            const int g = r * 4 + wave;
            __builtin_amdgcn_global_load_lds(
                (const AS1 unsigned int*)(A + (size_t)(bm + g * 8 + r8) * K + k0 + ksw),
                (AS3 unsigned int*)((AS3 char*)(AS3 bf16_t*)sA + g * 1024),
                16, 0, 0);
        }
#pragma unroll
        for (int r = 0; r < 4; r++) {               // B: 16 groups of 8 rows
            const int g = r * 4 + wave;
            __builtin_amdgcn_global_load_lds(
                (const AS1 unsigned int*)(BT + (size_t)(bn + g * 8 + r8) * K + k0 + ksw),
                (AS3 unsigned int*)((AS3 char*)(AS3 bf16_t*)sB + g * 1024),
                16, 0, 0);
        }
        __syncthreads();

#pragma unroll
        for (int s = 0; s < 2; s++) {               // two K=32 steps per BK=64
            bf16x8 af[4], bfr[4];
#pragma unroll
            for (int mt = 0; mt < 4; mt++) {
                const int R = wm + mt * 16 + lm;
                const int g = s * 4 + lq;
                af[mt] = *reinterpret_cast<bf16x8*>(&sA[R * 64 + ((g ^ (R & 7)) * 8)]);
            }
#pragma unroll
            for (int nt = 0; nt < 4; nt++) {
                const int R = wn + nt * 16 + lm;
                const int g = s * 4 + lq;
                bfr[nt] = *reinterpret_cast<bf16x8*>(&sB[R * 64 + ((g ^ (R & 7)) * 8)]);
            }
#pragma unroll
            for (int mt = 0; mt < 4; mt++)
#pragma unroll
                for (int nt = 0; nt < 4; nt++)
                    acc[mt][nt] = __builtin_amdgcn_mfma_f32_16x16x32_bf16(af[mt], bfr[nt], acc[mt][nt], 0, 0, 0);
        }
        __syncthreads();
    }

    if (!F32OUT) {
        const size_t rowbytes = (size_t)N * 2;
#pragma unroll
        for (int p = 0; p < 2; p++) {
            if (p) __syncthreads();
            if ((wave & 1) == p) {
#pragma unroll
                for (int nt = 0; nt < 4; nt++) {
                    const int col = wn + nt * 16 + lm;
                    const float bv = bias ? bias[bn + col] : 0.0f;
#pragma unroll
                    for (int mt = 0; mt < 4; mt++) {
#pragma unroll
                        for (int r = 0; r < 4; r++) {
                            const int lrow = mt * 16 + lq * 4 + r;
                            float v = acc[mt][nt][r] + bv;
                            if (rowscale) v *= rowscale[bm + p * 64 + lrow];
                            if (RELU) v = fmaxf(v, 0.0f);
                            sC[lrow * 136 + col] = (bf16_t)v;
                        }
                    }
                }
            }
            __syncthreads();
            char* outbase = (char*)Cv + (size_t)(bm + p * 64) * rowbytes + (size_t)bn * 2;
#pragma unroll
            for (int j = 0; j < 4; j++) {
                const int idx = j * 4096 + tid * 16;
                const int row = idx >> 8;            // 256 data bytes per row
                const int colb = idx & 255;
                *reinterpret_cast<uint4*>(outbase + (size_t)row * rowbytes + colb) =
                    *reinterpret_cast<const uint4*>((char*)sC + (size_t)row * 272 + colb);
            }
        }
    } else {
#pragma unroll
        for (int nt = 0; nt < 4; nt++) {
            const int col = bn + wn + nt * 16 + lm;
            const float bv = bias ? bias[col] : 0.0f;
#pragma unroll
            for (int mt = 0; mt < 4; mt++) {
#pragma unroll
                for (int r = 0; r < 4; r++) {
                    const int row = bm + wm + mt * 16 + lq * 4 + r;
                    if (row < M) {
                        float v = acc[mt][nt][r] + bv;
                        if (rowscale) v *= rowscale[row];
                        if (RELU) v = fmaxf(v, 0.0f);
                        ((float*)Cv)[(size_t)row * N + col] = v;
                    }
                }
            }
        }
    }
}

// ---------------- aggregation (persistent waves, cross-node pipeline) ----------------
// hw pre-scaled: hw[s] = dinv[s] * (h W)[s]. Slots padded to x4, dummies -> ZROW (zeros).
// h_out[n] = dinv[n] * ( hw[n] + sum_slots hw[s] ) + bias
// One wave handles a contiguous chunk of nodes; per node: self + 12 slot gathers
// (clamped to ZROW). Node n+1's indices+gathers are issued BEFORE consuming node n's,
// so the idx->gather dependent chain overlaps n's data arrival (vmcnt in-order:
// consuming buffer A waits only on A's older loads).

__device__ __forceinline__ void agg_issue(
    int n, const int* __restrict__ rs, const int* __restrict__ csr,
    const char* hwb, uint4 (&u)[13], int& beg, int& cnt)
{
    beg = rs[n];
    cnt = rs[n + 1] - beg;
    u[12] = *reinterpret_cast<const uint4*>(hwb + ((size_t)n << 10));
#pragma unroll
    for (int i = 0; i < 12; i++) {
        const int s = (i < cnt) ? csr[beg + i] : ZROW;
        u[i] = *reinterpret_cast<const uint4*>(hwb + ((size_t)s << 10));
    }
}

__device__ __forceinline__ void agg_consume(
    int n, const uint4 (&u)[13], int beg, int cnt,
    const int* __restrict__ csr, const char* hwb,
    const float* __restrict__ dinv, const float* bias_r,
    bf16_t* __restrict__ h_out, int lane)
{
    f32x2 acc[4] = {};
#pragma unroll
    for (int q = 0; q < 13; q++) {
        const unsigned* w = reinterpret_cast<const unsigned*>(&u[q]);
#pragma unroll
        for (int j = 0; j < 4; j++) {
            f32x2 v;
            v[0] = __uint_as_float(w[j] << 16);
            v[1] = __uint_as_float(w[j] & 0xffff0000u);
            acc[j] += v;
        }
    }
    for (int i = 12; i < cnt; i += 4) {           // rare tail (deg > 12)
        uint4 t[4];
#pragma unroll
        for (int q = 0; q < 4; q++) {
            const int s = (i + q < cnt) ? csr[beg + i + q] : ZROW;
            t[q] = *reinterpret_cast<const uint4*>(hwb + ((size_t)s << 10));
        }
#pragma unroll
        for (int q = 0; q < 4; q++) {
            const unsigned* w = reinterpret_cast<const unsigned*>(&t[q]);
#pragma unroll
            for (int j = 0; j < 4; j++) {
                f32x2 v;
                v[0] = __uint_as_float(w[j] << 16);
                v[1] = __uint_as_float(w[j] & 0xffff0000u);
                acc[j] += v;
            }
        }
    }
    const float dn = dinv[n];
    bf16_t outv[8];
#pragma unroll
    for (int j = 0; j < 4; j++) {
        outv[2 * j]     = (bf16_t)(fmaf(dn, acc[j][0], bias_r[2 * j]));
        outv[2 * j + 1] = (bf16_t)(fmaf(dn, acc[j][1], bias_r[2 * j + 1]));
    }
    *reinterpret_cast<uint4*>(h_out + (size_t)n * D_HID + lane * 8) =
        *reinterpret_cast<const uint4*>(outv);
}

__global__ __launch_bounds__(256) void aggregate(
    const bf16_t* __restrict__ hw, const float* __restrict__ dinv,
    const int* __restrict__ row_start, const int* __restrict__ csr_src,
    const float* __restrict__ bias, bf16_t* __restrict__ h_out, int N)
{
    const int lane = threadIdx.x & 63;
    const int wid = (blockIdx.x << 2) | (threadIdx.x >> 6);
    const int nw = gridDim.x << 2;
    const int per = (N + nw - 1) / nw;
    int n = wid * per;
    const int nend = (n + per < N) ? (n + per) : N;
    if (n >= nend) return;

    const char* hwb = (const char*)hw + lane * 16;
    float bias_r[8];
    {
        float4 b0 = *reinterpret_cast<const float4*>(bias + lane * 8);
        float4 b1 = *reinterpret_cast<const float4*>(bias + lane * 8 + 4);
        bias_r[0] = b0.x; bias_r[1] = b0.y; bias_r[2] = b0.z; bias_r[3] = b0.w;
        bias_r[4] = b1.x; bias_r[5] = b1.y; bias_r[6] = b1.z; bias_r[7] = b1.w;
    }

    uint4 ua[13], ub[13];
    int begA, cntA, begB, cntB;

    agg_issue(n, row_start, csr_src, hwb, ua, begA, cntA);
    while (true) {
        if (n + 1 < nend) agg_issue(n + 1, row_start, csr_src, hwb, ub, begB, cntB);
        agg_consume(n, ua, begA, cntA, csr_src, hwb, dinv, bias_r, h_out, lane);
        if (++n >= nend) break;
        if (n + 1 < nend) agg_issue(n + 1, row_start, csr_src, hwb, ua, begA, cntA);
        agg_consume(n, ub, begB, cntB, csr_src, hwb, dinv, bias_r, h_out, lane);
        if (++n >= nend) break;
    }
}

// ---------------- orchestration ----------------

extern "C" void kernel_launch(void* const* d_in, const int* in_sizes, int n_in,
                              void* d_out, int out_size, void* d_ws, size_t ws_size,
                              hipStream_t stream) {
    const int N = N_NODES, E = N_EDGES;

    const float* x  = (const float*)d_in[0];
    const int*   ei = (const int*)d_in[1];
    const float* W1 = (const float*)d_in[2];
    const float* b1 = (const float*)d_in[3];
    const float* Wc = (const float*)d_in[4];
    const float* bc = (const float*)d_in[5];
    const float* W2 = (const float*)d_in[6];
    const float* b2 = (const float*)d_in[7];
    float* out = (float*)d_out;

    char* ws = (char*)d_ws;
    size_t off = 0;
    auto alloc = [&](size_t bytes) -> void* {
        void* p = ws + off;
        off += (bytes + 255) & ~(size_t)255;
        return p;
    };
    int*    deg       = (int*)alloc((size_t)N * 4);
    int*    cursor    = (int*)alloc((size_t)N * 4);
    int*    row_start = (int*)alloc((size_t)(N + 1) * 4);
    int*    partial   = (int*)alloc(256 * 4);
    float*  dinv      = (float*)alloc((size_t)N_PAD * 4);
    int*    csr_src   = (int*)alloc((size_t)CSR_CAP * 4);
    bf16_t* h         = (bf16_t*)alloc((size_t)N_PAD * D_HID * 2);
    bf16_t* hw        = (bf16_t*)alloc((size_t)(N_PAD + 1) * D_HID * 2);  // +1: ZROW
    bf16_t* xb        = (bf16_t*)alloc((size_t)N_PAD * D_IN * 2);
    bf16_t* W1t       = (bf16_t*)alloc((size_t)D_HID * D_IN * 2);
    bf16_t* Wct       = (bf16_t*)alloc((size_t)N_LAYERS * D_HID * D_HID * 2);
    bf16_t* W2t       = (bf16_t*)alloc((size_t)D_OUT * D_HID * 2);

    init_misc<<<(CSR_CAP + 255) / 256, 256, 0, stream>>>(deg, cursor, csr_src, dinv, hw);

    {
        int n = N * D_IN;
        f32_to_bf16<<<(n / 4 + 255) / 256, 256, 0, stream>>>(x, xb, n);
        transpose_all<<<dim3(16, 16, 6), dim3(32, 8), 0, stream>>>(W1, Wc, W2, W1t, Wct, W2t);
    }

    count_deg<<<(E + 255) / 256, 256, 0, stream>>>(ei + E, deg, E);
    const int nch = (N + 1023) / 1024;
    scan_reduce<<<nch, 256, 0, stream>>>(deg, partial, N);
    scan_partials<<<1, 64, 0, stream>>>(partial, nch, row_start, N);
    scan_chunks<<<nch, 1024, 0, stream>>>(deg, partial, row_start, dinv, N);
    fill_csr<<<(E + 255) / 256, 256, 0, stream>>>(ei, E, row_start, cursor, csr_src);

    const dim3 blk(256);
    const int mg = N_PAD / 128;  // 391

    // dnn1: h = relu(x @ W1 + b1)
    gemm_tile<false, true><<<dim3(D_HID / 128, mg), blk, 0, stream>>>(
        xb, W1t, b1, nullptr, h, N_PAD, D_HID, D_IN);

    // GCN layers: hw = dinv .* (h @ Wc[i]); h = dinv .* (hw[self] + gather-sum) + bc[i]
    for (int i = 0; i < N_LAYERS; i++) {
        gemm_tile<false, false><<<dim3(D_HID / 128, mg), blk, 0, stream>>>(
            h, Wct + (size_t)i * D_HID * D_HID, nullptr, dinv, hw, N_PAD, D_HID, D_HID);
        aggregate<<<AGG_BLOCKS, 256, 0, stream>>>(hw, dinv, row_start, csr_src,
                                                  bc + (size_t)i * D_HID, h, N);
    }

    // dnn2: out = h @ W2 + b2 (fp32 out)
    gemm_tile<true, false><<<dim3(D_OUT / 128, mg), blk, 0, stream>>>(
        h, W2t, b2, nullptr, out, N, D_OUT, D_HID);
}